// Round 18
// baseline (156.795 us; speedup 1.0000x reference)
//
#include <hip/hip_runtime.h>
#include <math.h>
#include <stdint.h>

#define P_TOT 8192
#define CDIM  256
#define KC    50
#define NPIX  1024
#define TI    32
#define L2E   1.4426950408889634f

// pass1: 4 waves x 32 rows = 128 rows/block
#define RPBA  128
#define JSPA  32
#define JCHA  (P_TOT / JSPA)     // 256
#define NJSA  (JCHA / 32)        // 8
// pass2 (P-cached): 2 pairs x (32 rows x 128-col half); 64-j staging tiles
#define RPBC  64
#define JSPC  8
#define JCHC  (P_TOT / JSPC)     // 1024
#define NJSC  (JCHC / 64)        // 16 iterations of 64 j
// pass2 fallback (QK recompute)
#define RPBF  64
#define JSPF  8
#define JCHF  (P_TOT / JSPF)     // 1024
#define NJSF  (JCHF / 32)        // 32

#define SWZ8(r) (((r) & 7) << 4)

// workspace float offsets
#define OFF_NRM   0
#define OFF_Z     8192
#define OFF_S2    16384
#define OFF_THR   24576
#define OFF_DEN   32768
#define OFF_SCAL  40960
#define OFF_C2    41024
#define OFF_CT    41088    // [256][50] centers^T
#define OFF_XNB   65536    // [8192][256] bf16 normalized
#define OFF_XTB   1114112  // [256][8192] bf16 raw X^T
#define OFF_PART  65536    // [8][51][8192] f32 partials (aliases XNB/XTB/OUT pre-k2)
#define OFF_OUT   2162688  // [8192][256] f32 numerator
#define IOFF_BASE 4259840
#define II_ANOIDX 0
#define II_M      8192
#define II_CNTANO 8193
#define II_NMASK  8200     // [256] u32 normal-bitmask

#define PB_OFF    17104896ull           // byte offset of P buffer
#define WS_NEED   (PB_OFF + 67108864ull)

typedef __attribute__((ext_vector_type(8))) short short8;
typedef __attribute__((ext_vector_type(16))) float f32x16;

__device__ __forceinline__ ushort f2bf(float x) {
    union { float f; unsigned u; } v; v.f = x;
    unsigned r = v.u + 0x7fffu + ((v.u >> 16) & 1u);
    return (ushort)(r >> 16);
}
__device__ __forceinline__ unsigned cvtpk(float lo, float hi) {
    unsigned p;
    asm("v_cvt_pk_bf16_f32 %0, %1, %2" : "=v"(p) : "v"(lo), "v"(hi));
    return p;
}

typedef const __attribute__((address_space(1))) void gas_void;
typedef __attribute__((address_space(3))) void las_void;
__device__ __forceinline__ void gld_lds16(const void* g, void* l) {
    __builtin_amdgcn_global_load_lds(
        (gas_void*)(unsigned long long)(uintptr_t)g,
        (las_void*)(unsigned int)(uintptr_t)l, 16, 0, 0);
}

__global__ void k0_prep(const float* __restrict__ center, float* __restrict__ wsF) {
    int tid = threadIdx.x;
    float* cT = wsF + OFF_CT;
    for (int idx = tid; idx < KC * CDIM; idx += 256) {
        int k = idx / CDIM, c = idx % CDIM;
        cT[c * KC + k] = center[idx];
    }
    if (tid < 200) {
        int k = tid >> 2, q = tid & 3;
        float s = 0.f;
        const float* cp = center + k * CDIM + q * 64;
        for (int c = 0; c < 64; ++c) { float v = cp[c]; s += v * v; }
        s += __shfl_down(s, 2);
        s += __shfl_down(s, 1);
        if (q == 0) wsF[OFF_C2 + k] = s;
    }
}

__global__ __launch_bounds__(256) void k1a_dot(const float* __restrict__ f,
                                               const float* __restrict__ cT,
                                               float* __restrict__ PART) {
    int tid = threadIdx.x;
    int px = blockIdx.x * 256 + tid;
    int cg = blockIdx.y;             // 0..7
    int b = px >> 10, n = px & 1023;
    const float* fp = f + ((size_t)b * CDIM + cg * 32) * NPIX + n;
    float acc[KC];
#pragma unroll
    for (int k = 0; k < KC; ++k) acc[k] = 0.f;
    float x2 = 0.f;
    for (int cc = 0; cc < 32; ++cc) {
        float xv = fp[(size_t)cc * NPIX];
        x2 += xv * xv;
        const float* ct = cT + (cg * 32 + cc) * KC;
#pragma unroll
        for (int k = 0; k < KC; ++k) acc[k] = fmaf(xv, ct[k], acc[k]);
    }
    float* dst = PART + (size_t)cg * 51 * P_TOT + px;
#pragma unroll
    for (int k = 0; k < KC; ++k) dst[(size_t)k * P_TOT] = acc[k];
    dst[(size_t)50 * P_TOT] = x2;
}

__global__ __launch_bounds__(256) void k1b_min(const float* __restrict__ TcP,
                                               const float* __restrict__ c2g,
                                               const float* __restrict__ PART,
                                               float* __restrict__ wsF,
                                               int* __restrict__ wsI) {
    int tid = threadIdx.x;
    int px = blockIdx.x * 256 + tid;
    float x2 = 0.f;
#pragma unroll
    for (int g = 0; g < 8; ++g) x2 += PART[((size_t)g * 51 + 50) * P_TOT + px];
    float d2m = 3.4e38f;
#pragma unroll 10
    for (int k = 0; k < KC; ++k) {
        float s = PART[(size_t)k * P_TOT + px];
#pragma unroll
        for (int g = 1; g < 8; ++g) s += PART[((size_t)g * 51 + k) * P_TOT + px];
        float d2 = x2 + c2g[k] - 2.f * s;
        d2m = fminf(d2m, d2);
    }
    float d = sqrtf(fmaxf(d2m, 0.f));
    bool ano = d > TcP[0];
    wsF[OFF_NRM + px] = fmaxf(sqrtf(x2), 1e-8f);

    float dn = ano ? 0.f : d;
    float da = ano ? d : 0.f;
    for (int o = 32; o >= 1; o >>= 1) { dn += __shfl_down(dn, o); da += __shfl_down(da, o); }
    int lane = tid & 63;
    unsigned long long mask = __ballot(ano);
    int cnt = __popcll(mask);
    if (lane == 0) {
        atomicAdd(&wsF[OFF_SCAL + 0], dn);
        atomicAdd(&wsF[OFF_SCAL + 1], da);
        if (cnt) atomicAdd(&wsI[II_CNTANO], cnt);
        unsigned long long nm = ~mask;
        int w0 = px >> 5;
        wsI[II_NMASK + w0] = (int)(unsigned)nm;
        wsI[II_NMASK + w0 + 1] = (int)(unsigned)(nm >> 32);
    }
    if (ano) {
        int leader = __ffsll((unsigned long long)mask) - 1;
        int base = 0;
        if (lane == leader) base = atomicAdd(&wsI[II_M], cnt);
        base = __shfl(base, leader);
        int off = __popcll(mask & ((1ull << lane) - 1ull));
        wsI[II_ANOIDX + base + off] = px;
    }
}

// fused: bf16 convert + straight copy f -> out
__global__ void k2_convert(const float* __restrict__ f, float* __restrict__ out,
                           float* __restrict__ wsF) {
    __shared__ float t[32][33];
    int b = blockIdx.z, n0 = blockIdx.x * 32, c0 = blockIdx.y * 32;
    int tx = threadIdx.x, ty = threadIdx.y;
    const float* src = f + ((size_t)b * CDIM + c0) * NPIX + n0;
    float* dst = out + ((size_t)b * CDIM + c0) * NPIX + n0;
    ushort* XnB = (ushort*)(wsF + OFF_XNB);
    ushort* XTB = (ushort*)(wsF + OFF_XTB);
#pragma unroll
    for (int r = 0; r < 32; r += 8) {
        float v = src[(size_t)(ty + r) * NPIX + tx];
        t[ty + r][tx] = v;
        dst[(size_t)(ty + r) * NPIX + tx] = v;
        XTB[(size_t)(c0 + ty + r) * P_TOT + b * NPIX + n0 + tx] = f2bf(v);
    }
    __syncthreads();
#pragma unroll
    for (int r = 0; r < 32; r += 8) {
        int p = b * NPIX + n0 + ty + r;
        float nrm = wsF[OFF_NRM + p];
        XnB[(size_t)p * CDIM + c0 + tx] = f2bf(t[tx][ty + r] / nrm);
    }
}

// thr per ano row + Ld scalar (merged k3_ld)
__global__ void k4b_thr(float* __restrict__ out, float* __restrict__ wsF,
                        const int* __restrict__ wsI) {
    int Mv = wsI[II_M];
    int idx = blockIdx.x * 256 + threadIdx.x;
    if (idx == 0) {
        int cntAno = wsI[II_CNTANO];
        float cntNor = (float)(P_TOT - cntAno);
        float meanNor = wsF[OFF_SCAL + 0] / fmaxf(cntNor, 1.f);
        float meanAno = wsF[OFF_SCAL + 1] / fmaxf((float)cntAno, 1.f);
        out[P_TOT * CDIM] = (cntAno > 0) ? meanNor / (meanAno + 0.001f) : meanNor;
    }
    if (idx >= Mv) return;
    float t = fmaxf((float)(P_TOT - wsI[II_CNTANO]), 1.f);
    float Z = wsF[OFF_Z + idx], S2 = wsF[OFF_S2 + idx];
    float mu = 1.f / t;
    float var = S2 / (Z * Z * t) - mu * mu;
    wsF[OFF_THR + idx] = mu - 2.f * sqrtf(fmaxf(var, 0.f));
}

// pass1: swapped QK 32x32, Z/S2, P-fragment store (pre-packed PV-A bf16); 4 blocks/CU
__global__ __launch_bounds__(256, 4) void k5aP(float* __restrict__ wsF, const int* __restrict__ wsI,
                                               ushort* __restrict__ P, int writeP) {
    const int Mv = wsI[II_M];
    const int i0 = blockIdx.x * RPBA;
    if (i0 >= Mv) return;
    __shared__ __align__(16) ushort sK[2][32 * CDIM];   // 2 x 16KB
    const int tid = threadIdx.x;
    const int wave = tid >> 6, lane = tid & 63;
    const int jl = lane & 31, g = lane >> 5;
    const char* XnBb = (const char*)(wsF + OFF_XNB);
    const unsigned* nmask = (const unsigned*)(wsI + II_NMASK);
    const int* anoIdx = wsI + II_ANOIDX;
    const int jc0 = blockIdx.y * JCHA;
    const int iw = i0 + wave * 32;
    const int myrow = iw + jl;
    const int it = iw >> 5;

    short8 qf[16];
    {
        int arow = anoIdx[min(myrow, Mv - 1)];
#pragma unroll
        for (int kc = 0; kc < 16; ++kc)
            qf[kc] = *(const short8*)(XnBb + (size_t)arow * 512 + kc * 32 + g * 16);
    }
    float z = 0.f, s2 = 0.f;

    auto stageK = [&](int buf, int j0) {
#pragma unroll
        for (int itr = 0; itr < 4; ++itr) {
            int d = ((itr * 256 + tid) << 4);
            int row = d >> 9;
            int srco = (d & ~511) | ((d & 511) ^ SWZ8(row));
            gld_lds16(XnBb + ((size_t)j0 << 9) + srco, (char*)sK[buf] + d);
        }
    };

    stageK(0, jc0);
    __syncthreads();
    int cur = 0;
    for (int js = 0; js < NJSA; ++js) {
        int j0 = jc0 + js * 32;
        if (js + 1 < NJSA) stageK(cur ^ 1, j0 + 32);
        f32x16 acc;
#pragma unroll
        for (int r = 0; r < 16; ++r) acc[r] = 0.f;
#pragma unroll
        for (int kc = 0; kc < 16; ++kc) {
            int aoff = jl * 512 + ((kc * 32 + g * 16) ^ SWZ8(jl));
            short8 af = *(const short8*)((const char*)sK[cur] + aoff);
            acc = __builtin_amdgcn_mfma_f32_32x32x16_bf16(af, qf[kc], acc, 0, 0, 0);
        }
        unsigned um = nmask[j0 >> 5];
        float e[16];
#pragma unroll
        for (int r = 0; r < 16; ++r) {
            int jr = (r & 3) + 8 * (r >> 2) + 4 * g;
            e[r] = ((um >> jr) & 1u) ? __builtin_amdgcn_exp2f(fmaf(acc[r], L2E, -L2E)) : 0.f;
            z += e[r]; s2 = fmaf(e[r], e[r], s2);
        }
        if (writeP) {
            char* tile = (char*)P + ((size_t)it * 256 + (j0 >> 5)) * 2048;
#pragma unroll
            for (int kk = 0; kk < 2; ++kk) {
                int s = 8 * kk;
                unsigned p0 = cvtpk(e[s + 0], e[s + 1]);
                unsigned p1 = cvtpk(e[s + 2], e[s + 3]);
                unsigned p2 = cvtpk(e[s + 4], e[s + 5]);
                unsigned p3 = cvtpk(e[s + 6], e[s + 7]);
                unsigned o0 = (unsigned)__shfl_xor((int)p0, 32);
                unsigned o1 = (unsigned)__shfl_xor((int)p1, 32);
                unsigned o2 = (unsigned)__shfl_xor((int)p2, 32);
                unsigned o3 = (unsigned)__shfl_xor((int)p3, 32);
                union { unsigned u[4]; int4 v; } fr;
                fr.u[0] = g ? o2 : p0;
                fr.u[1] = g ? o3 : p1;
                fr.u[2] = g ? p2 : o0;
                fr.u[3] = g ? p3 : o1;
                *(int4*)(tile + kk * 1024 + lane * 16) = fr.v;
            }
        }
        __syncthreads();
        cur ^= 1;
    }
    z += __shfl_xor(z, 32);
    s2 += __shfl_xor(s2, 32);
    if (lane < 32 && myrow < Mv) {
        atomicAdd(&wsF[OFF_Z + myrow], z);
        atomicAdd(&wsF[OFF_S2 + myrow], s2);
    }
}

// pass2 (P-cached): 2 pairs x (32 rows x 128-col half); 64-j tiles; counted vmcnt
__global__ __launch_bounds__(256, 2) void k5cP(float* __restrict__ wsF, const int* __restrict__ wsI,
                                               const ushort* __restrict__ P) {
    const int Mv = wsI[II_M];
    const int i0 = blockIdx.x * RPBC;
    if (i0 >= Mv) return;
    __shared__ __align__(16) ushort sXT[2][CDIM * 64];   // 2 x 32KB
    const int tid = threadIdx.x;
    const int wave = tid >> 6, lane = tid & 63;
    const int jl = lane & 31, g = lane >> 5;
    const int pair = wave >> 1, ch = wave & 1;
    const char* XTBb = (const char*)(wsF + OFF_XTB);
    const int jc0 = blockIdx.y * JCHC;
    const int ibase = i0 + pair * 32;
    const int myrow = ibase + jl;
    const int it = ibase >> 5;
    const char* Pb = (const char*)P;

    float t2;
    {
        int ii = min(myrow, Mv - 1);
        t2 = wsF[OFF_Z + ii] * wsF[OFF_THR + ii];
    }
    float den = 0.f;
    f32x16 oAcc[4];
#pragma unroll
    for (int ct = 0; ct < 4; ++ct)
#pragma unroll
        for (int r = 0; r < 16; ++r) oAcc[ct][r] = 0.f;

    // stage 64 j-cols (two 32-j subtiles back-to-back, 32KB)
    auto stageX = [&](int buf, int j0) {
#pragma unroll
        for (int itr = 0; itr < 8; ++itr) {
            int d = ((itr * 256 + tid) << 4);   // 0..32KB
            int t = d >> 14;                     // subtile 0/1 (wave-uniform)
            int dd = d & 16383;
            int R = dd >> 7;
            int q = (dd & 127) ^ SWZ8(R);
            int c = 2 * R + (q >> 6);
            gld_lds16(XTBb + (size_t)c * (P_TOT * 2) + ((size_t)(j0 + 32 * t) << 1) + (q & 63),
                      (char*)sXT[buf] + d);
        }
    };
    auto ldP = [&](int jt, int kk) {
        return *(const int4*)(Pb + ((size_t)it * 256 + jt) * 2048 + kk * 1024 + lane * 16);
    };

    int4 a[4];
    // prologue: stage first (oldest), then P loads; drain stage only
    stageX(0, jc0);
    {
        int jt = jc0 >> 5;
        a[0] = ldP(jt, 0); a[1] = ldP(jt, 1);
        a[2] = ldP(jt + 1, 0); a[3] = ldP(jt + 1, 1);
    }
    asm volatile("s_waitcnt vmcnt(4)" ::: "memory");
    __builtin_amdgcn_sched_barrier(0);
    __builtin_amdgcn_s_barrier();
    __builtin_amdgcn_sched_barrier(0);
    int cur = 0;
    for (int js = 0; js < NJSC; ++js) {
        int j0 = jc0 + js * 64;
        int4 n[4];
        if (js + 1 < NJSC) {
            stageX(cur ^ 1, j0 + 64);
            int jt = (j0 >> 5) + 2;
            n[0] = ldP(jt, 0); n[1] = ldP(jt, 1);
            n[2] = ldP(jt + 1, 0); n[3] = ldP(jt + 1, 1);
        }
#pragma unroll
        for (int sub = 0; sub < 2; ++sub) {
            union { int4 v; unsigned u[4]; } A0, A1;
            A0.v = a[2 * sub]; A1.v = a[2 * sub + 1];
#pragma unroll
            for (int q = 0; q < 4; ++q) {
                unsigned u0 = A0.u[q], u1 = A1.u[q];
                float l0 = __uint_as_float(u0 << 16), h0 = __uint_as_float(u0 & 0xffff0000u);
                float l1 = __uint_as_float(u1 << 16), h1 = __uint_as_float(u1 & 0xffff0000u);
                bool lk0 = l0 > t2, hk0 = h0 > t2, lk1 = l1 > t2, hk1 = h1 > t2;
                den += (lk0 ? l0 : 0.f) + (hk0 ? h0 : 0.f) + (lk1 ? l1 : 0.f) + (hk1 ? h1 : 0.f);
                A0.u[q] = (lk0 ? (u0 & 0xffffu) : 0u) | (hk0 ? (u0 & 0xffff0000u) : 0u);
                A1.u[q] = (lk1 ? (u1 & 0xffffu) : 0u) | (hk1 ? (u1 & 0xffff0000u) : 0u);
            }
            union { int4 v; short8 s; } F0, F1;
            F0.v = A0.v; F1.v = A1.v;
            const char* base = (const char*)sXT[cur] + sub * 16384;
#pragma unroll
            for (int ct = 0; ct < 4; ++ct) {
                int c = ch * 128 + ct * 32 + jl;
                int R = c >> 1;
                int off0 = (((c & 1) << 6) | (16 * g)) ^ SWZ8(R);
                int off1 = (((c & 1) << 6) | (32 + 16 * g)) ^ SWZ8(R);
                short8 bf0 = *(const short8*)(base + R * 128 + off0);
                short8 bf1 = *(const short8*)(base + R * 128 + off1);
                oAcc[ct] = __builtin_amdgcn_mfma_f32_32x32x16_bf16(F0.s, bf0, oAcc[ct], 0, 0, 0);
                oAcc[ct] = __builtin_amdgcn_mfma_f32_32x32x16_bf16(F1.s, bf1, oAcc[ct], 0, 0, 0);
            }
        }
        // drain only this iter's 8 stage ops (oldest); keep 4 P loads in flight
        asm volatile("s_waitcnt vmcnt(4)" ::: "memory");
        __builtin_amdgcn_sched_barrier(0);
        __builtin_amdgcn_s_barrier();
        __builtin_amdgcn_sched_barrier(0);
        cur ^= 1;
        a[0] = n[0]; a[1] = n[1]; a[2] = n[2]; a[3] = n[3];
    }

    den += __shfl_xor(den, 32);
    if (ch == 0 && lane < 32 && myrow < Mv)
        atomicAdd(&wsF[OFF_DEN + myrow], den);
#pragma unroll
    for (int ct = 0; ct < 4; ++ct) {
        int col = ch * 128 + ct * 32 + jl;
#pragma unroll
        for (int r = 0; r < 16; ++r) {
            int row = ibase + (r & 3) + 8 * (r >> 2) + 4 * g;
            if (row < Mv)
                atomicAdd(&wsF[OFF_OUT + (size_t)row * CDIM + col], oAcc[ct][r]);
        }
    }
}

// pass2 fallback: recompute QK (R9 structure)
__global__ __launch_bounds__(256, 2) void k5c_full(float* __restrict__ wsF, const int* __restrict__ wsI) {
    const int Mv = wsI[II_M];
    const int i0 = blockIdx.x * RPBF;
    if (i0 >= Mv) return;
    __shared__ __align__(16) ushort sK[2][32 * CDIM];
    __shared__ __align__(16) ushort sXT[2][CDIM * 32];
    const int tid = threadIdx.x;
    const int wave = tid >> 6, lane = tid & 63;
    const int jl = lane & 31, g = lane >> 5;
    const int pair = wave >> 1, ch = wave & 1;
    const char* XnBb = (const char*)(wsF + OFF_XNB);
    const char* XTBb = (const char*)(wsF + OFF_XTB);
    const unsigned* nmask = (const unsigned*)(wsI + II_NMASK);
    const int* anoIdx = wsI + II_ANOIDX;
    const int jc0 = blockIdx.y * JCHF;
    const int ibase = i0 + pair * 32;
    const int myrow = ibase + jl;

    short8 qf[16];
    float ec, thr;
    {
        int ii = min(myrow, Mv - 1);
        int arow = anoIdx[ii];
#pragma unroll
        for (int kc = 0; kc < 16; ++kc)
            qf[kc] = *(const short8*)(XnBb + (size_t)arow * 512 + kc * 32 + g * 16);
        ec = -__log2f(wsF[OFF_Z + ii]) - L2E;
        thr = wsF[OFF_THR + ii];
    }
    float den = 0.f;
    f32x16 oAcc[4];
#pragma unroll
    for (int ct = 0; ct < 4; ++ct)
#pragma unroll
        for (int r = 0; r < 16; ++r) oAcc[ct][r] = 0.f;

    auto stageK = [&](int buf, int j0) {
#pragma unroll
        for (int itr = 0; itr < 4; ++itr) {
            int d = ((itr * 256 + tid) << 4);
            int row = d >> 9;
            int srco = (d & ~511) | ((d & 511) ^ SWZ8(row));
            gld_lds16(XnBb + ((size_t)j0 << 9) + srco, (char*)sK[buf] + d);
        }
    };
    auto stageX = [&](int buf, int j0) {
#pragma unroll
        for (int itr = 0; itr < 4; ++itr) {
            int d = ((itr * 256 + tid) << 4);
            int R = d >> 7;
            int q = (d & 127) ^ SWZ8(R);
            int c = 2 * R + (q >> 6);
            gld_lds16(XTBb + (size_t)c * (P_TOT * 2) + ((size_t)j0 << 1) + (q & 63),
                      (char*)sXT[buf] + d);
        }
    };

    stageK(0, jc0);
    stageX(0, jc0);
    __syncthreads();
    int cur = 0;
    for (int js = 0; js < NJSF; ++js) {
        int j0 = jc0 + js * 32;
        if (js + 1 < NJSF) { stageK(cur ^ 1, j0 + 32); stageX(cur ^ 1, j0 + 32); }
        f32x16 acc;
#pragma unroll
        for (int r = 0; r < 16; ++r) acc[r] = 0.f;
#pragma unroll
        for (int kc = 0; kc < 16; ++kc) {
            int aoff = jl * 512 + ((kc * 32 + g * 16) ^ SWZ8(jl));
            short8 af = *(const short8*)((const char*)sK[cur] + aoff);
            acc = __builtin_amdgcn_mfma_f32_32x32x16_bf16(af, qf[kc], acc, 0, 0, 0);
        }
        unsigned um = nmask[j0 >> 5];
        float sw[16];
#pragma unroll
        for (int r = 0; r < 16; ++r) {
            int jr = (r & 3) + 8 * (r >> 2) + 4 * g;
            float w = __builtin_amdgcn_exp2f(fmaf(acc[r], L2E, ec));
            bool ok = (((um >> jr) & 1u) != 0u) && (w > thr);
            sw[r] = ok ? w : 0.f;
            den += sw[r];
        }
#pragma unroll
        for (int kk = 0; kk < 2; ++kk) {
            int s = 8 * kk;
            unsigned p0 = cvtpk(sw[s + 0], sw[s + 1]);
            unsigned p1 = cvtpk(sw[s + 2], sw[s + 3]);
            unsigned p2 = cvtpk(sw[s + 4], sw[s + 5]);
            unsigned p3 = cvtpk(sw[s + 6], sw[s + 7]);
            unsigned o0 = (unsigned)__shfl_xor((int)p0, 32);
            unsigned o1 = (unsigned)__shfl_xor((int)p1, 32);
            unsigned o2 = (unsigned)__shfl_xor((int)p2, 32);
            unsigned o3 = (unsigned)__shfl_xor((int)p3, 32);
            union { unsigned u[4]; short8 v; } fr;
            fr.u[0] = g ? o2 : p0;
            fr.u[1] = g ? o3 : p1;
            fr.u[2] = g ? p2 : o0;
            fr.u[3] = g ? p3 : o1;
#pragma unroll
            for (int ct = 0; ct < 4; ++ct) {
                int c = ch * 128 + ct * 32 + jl;
                int R = c >> 1;
                int off = (((c & 1) << 6) | (32 * kk + 16 * g)) ^ SWZ8(R);
                short8 bf = *(const short8*)((const char*)sXT[cur] + R * 128 + off);
                oAcc[ct] = __builtin_amdgcn_mfma_f32_32x32x16_bf16(fr.v, bf, oAcc[ct], 0, 0, 0);
            }
        }
        __syncthreads();
        cur ^= 1;
    }

    den += __shfl_xor(den, 32);
    if (ch == 0 && lane < 32 && myrow < Mv)
        atomicAdd(&wsF[OFF_DEN + myrow], den);
#pragma unroll
    for (int ct = 0; ct < 4; ++ct) {
        int col = ch * 128 + ct * 32 + jl;
#pragma unroll
        for (int r = 0; r < 16; ++r) {
            int row = ibase + (r & 3) + 8 * (r >> 2) + 4 * g;
            if (row < Mv)
                atomicAdd(&wsF[OFF_OUT + (size_t)row * CDIM + col], oAcc[ct][r]);
        }
    }
}

__global__ void k4d_final(float* __restrict__ out, const float* __restrict__ wsF,
                          const int* __restrict__ wsI) {
    int Mv = wsI[II_M];
    int i0 = blockIdx.x * TI;
    if (i0 >= Mv) return;
    int tid = threadIdx.x;
    int ii = tid >> 3, cg = tid & 7;
    int i = i0 + ii;
    if (i >= Mv) return;
    int p = wsI[II_ANOIDX + i];
    int b = p >> 10, n = p & 1023;
    float rden = 1.f / wsF[OFF_DEN + i];
    const float* go = wsF + OFF_OUT + (size_t)i * CDIM;
    float* op = out + (size_t)b * CDIM * NPIX + n;
#pragma unroll
    for (int cc = 0; cc < 32; ++cc) {
        int c = cc * 8 + cg;
        op[(size_t)c * NPIX] = go[c] * rden;
    }
}

extern "C" void kernel_launch(void* const* d_in, const int* in_sizes, int n_in,
                              void* d_out, int out_size, void* d_ws, size_t ws_size,
                              hipStream_t stream) {
    const float* f = (const float*)d_in[0];
    const float* center = (const float*)d_in[1];
    const float* Tc = (const float*)d_in[2];
    float* out = (float*)d_out;
    float* wsF = (float*)d_ws;
    int* wsI = (int*)(wsF + IOFF_BASE);
    const bool big = ws_size >= WS_NEED;
    ushort* Pbuf = (ushort*)((char*)d_ws + PB_OFF);

    hipMemsetAsync(wsF + OFF_Z, 0, (OFF_CT - OFF_Z) * sizeof(float), stream);
    hipMemsetAsync(wsI + II_M, 0, 2 * sizeof(int), stream);

    k0_prep<<<1, 256, 0, stream>>>(center, wsF);
    dim3 g1a(32, 8);
    k1a_dot<<<g1a, 256, 0, stream>>>(f, wsF + OFF_CT, wsF + OFF_PART);
    k1b_min<<<32, 256, 0, stream>>>(Tc, wsF + OFF_C2, wsF + OFF_PART, wsF, wsI);
    // OUT memset must come after k1b (PART aliases the OUT region)
    hipMemsetAsync(wsF + OFF_OUT, 0, (size_t)P_TOT * CDIM * sizeof(float), stream);
    dim3 g2(32, 8, 8), b2(32, 8);
    k2_convert<<<g2, b2, 0, stream>>>(f, out, wsF);
    dim3 g5a(P_TOT / RPBA, JSPA);
    k5aP<<<g5a, 256, 0, stream>>>(wsF, wsI, Pbuf, big ? 1 : 0);
    k4b_thr<<<P_TOT / 256, 256, 0, stream>>>(out, wsF, wsI);
    if (big) {
        dim3 g5c(P_TOT / RPBC, JSPC);
        k5cP<<<g5c, 256, 0, stream>>>(wsF, wsI, Pbuf);
    } else {
        dim3 g5c(P_TOT / RPBF, JSPF);
        k5c_full<<<g5c, 256, 0, stream>>>(wsF, wsI);
    }
    k4d_final<<<P_TOT / TI, 256, 0, stream>>>(out, wsF, wsI);
}

// Round 19
// 153.995 us; speedup vs baseline: 1.0182x; 1.0182x over previous
//
#include <hip/hip_runtime.h>
#include <math.h>
#include <stdint.h>

#define P_TOT 8192
#define CDIM  256
#define KC    50
#define NPIX  1024
#define TI    32
#define L2E   1.4426950408889634f

// pass1: 4 waves x 32 rows = 128 rows/block
#define RPBA  128
#define JSPA  32
#define JCHA  (P_TOT / JSPA)     // 256
#define NJSA  (JCHA / 32)        // 8
// pass2 (P-cached): 2 pairs x (32 rows x 128-col half); 64-j staging tiles
#define RPBC  64
#define JSPC  8
#define JCHC  (P_TOT / JSPC)     // 1024
#define NJSC  (JCHC / 64)        // 16 iterations of 64 j
// pass2 fallback (QK recompute)
#define RPBF  64
#define JSPF  8
#define JCHF  (P_TOT / JSPF)     // 1024
#define NJSF  (JCHF / 32)        // 32

#define SWZ8(r) (((r) & 7) << 4)

// workspace float offsets
#define OFF_NRM   0
#define OFF_Z     8192
#define OFF_S2    16384
#define OFF_THR   24576
#define OFF_DEN   32768
#define OFF_SCAL  40960
#define OFF_C2    41024
#define OFF_CT    41088    // [256][50] centers^T
#define OFF_XNB   65536    // [8192][256] bf16 normalized
#define OFF_XTB   1114112  // [256][8192] bf16 raw X^T
#define OFF_PART  65536    // [8][51][8192] f32 partials (aliases XNB/XTB/OUT pre-k2)
#define OFF_OUT   2162688  // [8192][256] f32 numerator
#define IOFF_BASE 4259840
#define II_ANOIDX 0
#define II_M      8192
#define II_CNTANO 8193
#define II_NMASK  8200     // [256] u32 normal-bitmask

#define PB_OFF    17104896ull           // byte offset of P buffer
#define WS_NEED   (PB_OFF + 67108864ull)

typedef __attribute__((ext_vector_type(8))) short short8;
typedef __attribute__((ext_vector_type(16))) float f32x16;

__device__ __forceinline__ ushort f2bf(float x) {
    union { float f; unsigned u; } v; v.f = x;
    unsigned r = v.u + 0x7fffu + ((v.u >> 16) & 1u);
    return (ushort)(r >> 16);
}
__device__ __forceinline__ unsigned cvtpk(float lo, float hi) {
    unsigned p;
    asm("v_cvt_pk_bf16_f32 %0, %1, %2" : "=v"(p) : "v"(lo), "v"(hi));
    return p;
}

typedef const __attribute__((address_space(1))) void gas_void;
typedef __attribute__((address_space(3))) void las_void;
__device__ __forceinline__ void gld_lds16(const void* g, void* l) {
    __builtin_amdgcn_global_load_lds(
        (gas_void*)(unsigned long long)(uintptr_t)g,
        (las_void*)(unsigned int)(uintptr_t)l, 16, 0, 0);
}

__global__ void k0_prep(const float* __restrict__ center, float* __restrict__ wsF) {
    int tid = threadIdx.x;
    float* cT = wsF + OFF_CT;
    for (int idx = tid; idx < KC * CDIM; idx += 256) {
        int k = idx / CDIM, c = idx % CDIM;
        cT[c * KC + k] = center[idx];
    }
    if (tid < 200) {
        int k = tid >> 2, q = tid & 3;
        float s = 0.f;
        const float* cp = center + k * CDIM + q * 64;
        for (int c = 0; c < 64; ++c) { float v = cp[c]; s += v * v; }
        s += __shfl_down(s, 2);
        s += __shfl_down(s, 1);
        if (q == 0) wsF[OFF_C2 + k] = s;
    }
}

__global__ __launch_bounds__(256) void k1a_dot(const float* __restrict__ f,
                                               const float* __restrict__ cT,
                                               float* __restrict__ PART) {
    int tid = threadIdx.x;
    int px = blockIdx.x * 256 + tid;
    int cg = blockIdx.y;             // 0..7
    int b = px >> 10, n = px & 1023;
    const float* fp = f + ((size_t)b * CDIM + cg * 32) * NPIX + n;
    float acc[KC];
#pragma unroll
    for (int k = 0; k < KC; ++k) acc[k] = 0.f;
    float x2 = 0.f;
    for (int cc = 0; cc < 32; ++cc) {
        float xv = fp[(size_t)cc * NPIX];
        x2 += xv * xv;
        const float* ct = cT + (cg * 32 + cc) * KC;
#pragma unroll
        for (int k = 0; k < KC; ++k) acc[k] = fmaf(xv, ct[k], acc[k]);
    }
    float* dst = PART + (size_t)cg * 51 * P_TOT + px;
#pragma unroll
    for (int k = 0; k < KC; ++k) dst[(size_t)k * P_TOT] = acc[k];
    dst[(size_t)50 * P_TOT] = x2;
}

__global__ __launch_bounds__(256) void k1b_min(const float* __restrict__ TcP,
                                               const float* __restrict__ c2g,
                                               const float* __restrict__ PART,
                                               float* __restrict__ wsF,
                                               int* __restrict__ wsI) {
    int tid = threadIdx.x;
    int px = blockIdx.x * 256 + tid;
    float x2 = 0.f;
#pragma unroll
    for (int g = 0; g < 8; ++g) x2 += PART[((size_t)g * 51 + 50) * P_TOT + px];
    float d2m = 3.4e38f;
#pragma unroll 10
    for (int k = 0; k < KC; ++k) {
        float s = PART[(size_t)k * P_TOT + px];
#pragma unroll
        for (int g = 1; g < 8; ++g) s += PART[((size_t)g * 51 + k) * P_TOT + px];
        float d2 = x2 + c2g[k] - 2.f * s;
        d2m = fminf(d2m, d2);
    }
    float d = sqrtf(fmaxf(d2m, 0.f));
    bool ano = d > TcP[0];
    wsF[OFF_NRM + px] = fmaxf(sqrtf(x2), 1e-8f);

    float dn = ano ? 0.f : d;
    float da = ano ? d : 0.f;
    for (int o = 32; o >= 1; o >>= 1) { dn += __shfl_down(dn, o); da += __shfl_down(da, o); }
    int lane = tid & 63;
    unsigned long long mask = __ballot(ano);
    int cnt = __popcll(mask);
    if (lane == 0) {
        atomicAdd(&wsF[OFF_SCAL + 0], dn);
        atomicAdd(&wsF[OFF_SCAL + 1], da);
        if (cnt) atomicAdd(&wsI[II_CNTANO], cnt);
        unsigned long long nm = ~mask;
        int w0 = px >> 5;
        wsI[II_NMASK + w0] = (int)(unsigned)nm;
        wsI[II_NMASK + w0 + 1] = (int)(unsigned)(nm >> 32);
    }
    if (ano) {
        int leader = __ffsll((unsigned long long)mask) - 1;
        int base = 0;
        if (lane == leader) base = atomicAdd(&wsI[II_M], cnt);
        base = __shfl(base, leader);
        int off = __popcll(mask & ((1ull << lane) - 1ull));
        wsI[II_ANOIDX + base + off] = px;
    }
}

// fused: bf16 convert + straight copy f -> out
__global__ void k2_convert(const float* __restrict__ f, float* __restrict__ out,
                           float* __restrict__ wsF) {
    __shared__ float t[32][33];
    int b = blockIdx.z, n0 = blockIdx.x * 32, c0 = blockIdx.y * 32;
    int tx = threadIdx.x, ty = threadIdx.y;
    const float* src = f + ((size_t)b * CDIM + c0) * NPIX + n0;
    float* dst = out + ((size_t)b * CDIM + c0) * NPIX + n0;
    ushort* XnB = (ushort*)(wsF + OFF_XNB);
    ushort* XTB = (ushort*)(wsF + OFF_XTB);
#pragma unroll
    for (int r = 0; r < 32; r += 8) {
        float v = src[(size_t)(ty + r) * NPIX + tx];
        t[ty + r][tx] = v;
        dst[(size_t)(ty + r) * NPIX + tx] = v;
        XTB[(size_t)(c0 + ty + r) * P_TOT + b * NPIX + n0 + tx] = f2bf(v);
    }
    __syncthreads();
#pragma unroll
    for (int r = 0; r < 32; r += 8) {
        int p = b * NPIX + n0 + ty + r;
        float nrm = wsF[OFF_NRM + p];
        XnB[(size_t)p * CDIM + c0 + tx] = f2bf(t[tx][ty + r] / nrm);
    }
}

__global__ void k3_ld(float* __restrict__ out, const float* __restrict__ wsF,
                      const int* __restrict__ wsI) {
    int cntAno = wsI[II_CNTANO];
    float cntNor = (float)(P_TOT - cntAno);
    float meanNor = wsF[OFF_SCAL + 0] / fmaxf(cntNor, 1.f);
    float meanAno = wsF[OFF_SCAL + 1] / fmaxf((float)cntAno, 1.f);
    out[P_TOT * CDIM] = (cntAno > 0) ? meanNor / (meanAno + 0.001f) : meanNor;
}

// pass1: swapped QK 32x32, Z/S2, P-fragment store (pre-packed PV-A bf16)
__global__ __launch_bounds__(256, 3) void k5aP(float* __restrict__ wsF, const int* __restrict__ wsI,
                                               ushort* __restrict__ P, int writeP) {
    const int Mv = wsI[II_M];
    const int i0 = blockIdx.x * RPBA;
    if (i0 >= Mv) return;
    __shared__ __align__(16) ushort sK[2][32 * CDIM];   // 2 x 16KB
    const int tid = threadIdx.x;
    const int wave = tid >> 6, lane = tid & 63;
    const int jl = lane & 31, g = lane >> 5;
    const char* XnBb = (const char*)(wsF + OFF_XNB);
    const unsigned* nmask = (const unsigned*)(wsI + II_NMASK);
    const int* anoIdx = wsI + II_ANOIDX;
    const int jc0 = blockIdx.y * JCHA;
    const int iw = i0 + wave * 32;
    const int myrow = iw + jl;
    const int it = iw >> 5;

    short8 qf[16];
    {
        int arow = anoIdx[min(myrow, Mv - 1)];
#pragma unroll
        for (int kc = 0; kc < 16; ++kc)
            qf[kc] = *(const short8*)(XnBb + (size_t)arow * 512 + kc * 32 + g * 16);
    }
    float z = 0.f, s2 = 0.f;

    auto stageK = [&](int buf, int j0) {
#pragma unroll
        for (int itr = 0; itr < 4; ++itr) {
            int d = ((itr * 256 + tid) << 4);
            int row = d >> 9;
            int srco = (d & ~511) | ((d & 511) ^ SWZ8(row));
            gld_lds16(XnBb + ((size_t)j0 << 9) + srco, (char*)sK[buf] + d);
        }
    };

    stageK(0, jc0);
    __syncthreads();
    int cur = 0;
    for (int js = 0; js < NJSA; ++js) {
        int j0 = jc0 + js * 32;
        if (js + 1 < NJSA) stageK(cur ^ 1, j0 + 32);
        f32x16 acc;
#pragma unroll
        for (int r = 0; r < 16; ++r) acc[r] = 0.f;
#pragma unroll
        for (int kc = 0; kc < 16; ++kc) {
            int aoff = jl * 512 + ((kc * 32 + g * 16) ^ SWZ8(jl));
            short8 af = *(const short8*)((const char*)sK[cur] + aoff);
            acc = __builtin_amdgcn_mfma_f32_32x32x16_bf16(af, qf[kc], acc, 0, 0, 0);
        }
        unsigned um = nmask[j0 >> 5];
        float e[16];
#pragma unroll
        for (int r = 0; r < 16; ++r) {
            int jr = (r & 3) + 8 * (r >> 2) + 4 * g;
            e[r] = ((um >> jr) & 1u) ? __builtin_amdgcn_exp2f(fmaf(acc[r], L2E, -L2E)) : 0.f;
            z += e[r]; s2 = fmaf(e[r], e[r], s2);
        }
        if (writeP) {
            char* tile = (char*)P + ((size_t)it * 256 + (j0 >> 5)) * 2048;
#pragma unroll
            for (int kk = 0; kk < 2; ++kk) {
                int s = 8 * kk;
                unsigned p0 = cvtpk(e[s + 0], e[s + 1]);
                unsigned p1 = cvtpk(e[s + 2], e[s + 3]);
                unsigned p2 = cvtpk(e[s + 4], e[s + 5]);
                unsigned p3 = cvtpk(e[s + 6], e[s + 7]);
                unsigned o0 = (unsigned)__shfl_xor((int)p0, 32);
                unsigned o1 = (unsigned)__shfl_xor((int)p1, 32);
                unsigned o2 = (unsigned)__shfl_xor((int)p2, 32);
                unsigned o3 = (unsigned)__shfl_xor((int)p3, 32);
                union { unsigned u[4]; int4 v; } fr;
                fr.u[0] = g ? o2 : p0;
                fr.u[1] = g ? o3 : p1;
                fr.u[2] = g ? p2 : o0;
                fr.u[3] = g ? p3 : o1;
                *(int4*)(tile + kk * 1024 + lane * 16) = fr.v;
            }
        }
        __syncthreads();
        cur ^= 1;
    }
    z += __shfl_xor(z, 32);
    s2 += __shfl_xor(s2, 32);
    if (lane < 32 && myrow < Mv) {
        atomicAdd(&wsF[OFF_Z + myrow], z);
        atomicAdd(&wsF[OFF_S2 + myrow], s2);
    }
}

__global__ void k4b_thr(float* __restrict__ wsF, const int* __restrict__ wsI) {
    int Mv = wsI[II_M];
    int idx = blockIdx.x * 256 + threadIdx.x;
    if (idx >= Mv) return;
    float t = fmaxf((float)(P_TOT - wsI[II_CNTANO]), 1.f);
    float Z = wsF[OFF_Z + idx], S2 = wsF[OFF_S2 + idx];
    float mu = 1.f / t;
    float var = S2 / (Z * Z * t) - mu * mu;
    wsF[OFF_THR + idx] = mu - 2.f * sqrtf(fmaxf(var, 0.f));
}

// pass2 (P-cached): 2 pairs x (32 rows x 128-col half); 64-j tiles; counted vmcnt
// 1-D grid, y = lid & 7 -> same-y blocks share an XCD (L2 keeps one XTB chunk)
__global__ __launch_bounds__(256, 2) void k5cP(float* __restrict__ wsF, const int* __restrict__ wsI,
                                               const ushort* __restrict__ P) {
    const int Mv = wsI[II_M];
    const int lid = blockIdx.x;
    const int by = lid & 7;            // XCD-affine j-split index
    const int bx = lid >> 3;           // i-tile index
    const int i0 = bx * RPBC;
    if (i0 >= Mv) return;
    __shared__ __align__(16) ushort sXT[2][CDIM * 64];   // 2 x 32KB
    const int tid = threadIdx.x;
    const int wave = tid >> 6, lane = tid & 63;
    const int jl = lane & 31, g = lane >> 5;
    const int pair = wave >> 1, ch = wave & 1;
    const char* XTBb = (const char*)(wsF + OFF_XTB);
    const int jc0 = by * JCHC;
    const int ibase = i0 + pair * 32;
    const int myrow = ibase + jl;
    const int it = ibase >> 5;
    const char* Pb = (const char*)P;

    float t2;
    {
        int ii = min(myrow, Mv - 1);
        t2 = wsF[OFF_Z + ii] * wsF[OFF_THR + ii];
    }
    float den = 0.f;
    f32x16 oAcc[4];
#pragma unroll
    for (int ct = 0; ct < 4; ++ct)
#pragma unroll
        for (int r = 0; r < 16; ++r) oAcc[ct][r] = 0.f;

    // stage 64 j-cols (two 32-j subtiles back-to-back, 32KB)
    auto stageX = [&](int buf, int j0) {
#pragma unroll
        for (int itr = 0; itr < 8; ++itr) {
            int d = ((itr * 256 + tid) << 4);   // 0..32KB
            int t = d >> 14;                     // subtile 0/1 (wave-uniform)
            int dd = d & 16383;
            int R = dd >> 7;
            int q = (dd & 127) ^ SWZ8(R);
            int c = 2 * R + (q >> 6);
            gld_lds16(XTBb + (size_t)c * (P_TOT * 2) + ((size_t)(j0 + 32 * t) << 1) + (q & 63),
                      (char*)sXT[buf] + d);
        }
    };
    auto ldP = [&](int jt, int kk) {
        return *(const int4*)(Pb + ((size_t)it * 256 + jt) * 2048 + kk * 1024 + lane * 16);
    };

    int4 a[4];
    // prologue: stage first (oldest), then P loads; drain stage only
    stageX(0, jc0);
    {
        int jt = jc0 >> 5;
        a[0] = ldP(jt, 0); a[1] = ldP(jt, 1);
        a[2] = ldP(jt + 1, 0); a[3] = ldP(jt + 1, 1);
    }
    asm volatile("s_waitcnt vmcnt(4)" ::: "memory");
    __builtin_amdgcn_sched_barrier(0);
    __builtin_amdgcn_s_barrier();
    __builtin_amdgcn_sched_barrier(0);
    int cur = 0;
    for (int js = 0; js < NJSC; ++js) {
        int j0 = jc0 + js * 64;
        int4 n[4];
        if (js + 1 < NJSC) {
            stageX(cur ^ 1, j0 + 64);
            int jt = (j0 >> 5) + 2;
            n[0] = ldP(jt, 0); n[1] = ldP(jt, 1);
            n[2] = ldP(jt + 1, 0); n[3] = ldP(jt + 1, 1);
        }
#pragma unroll
        for (int sub = 0; sub < 2; ++sub) {
            union { int4 v; unsigned u[4]; } A0, A1;
            A0.v = a[2 * sub]; A1.v = a[2 * sub + 1];
#pragma unroll
            for (int q = 0; q < 4; ++q) {
                unsigned u0 = A0.u[q], u1 = A1.u[q];
                float l0 = __uint_as_float(u0 << 16), h0 = __uint_as_float(u0 & 0xffff0000u);
                float l1 = __uint_as_float(u1 << 16), h1 = __uint_as_float(u1 & 0xffff0000u);
                bool lk0 = l0 > t2, hk0 = h0 > t2, lk1 = l1 > t2, hk1 = h1 > t2;
                den += (lk0 ? l0 : 0.f) + (hk0 ? h0 : 0.f) + (lk1 ? l1 : 0.f) + (hk1 ? h1 : 0.f);
                A0.u[q] = (lk0 ? (u0 & 0xffffu) : 0u) | (hk0 ? (u0 & 0xffff0000u) : 0u);
                A1.u[q] = (lk1 ? (u1 & 0xffffu) : 0u) | (hk1 ? (u1 & 0xffff0000u) : 0u);
            }
            union { int4 v; short8 s; } F0, F1;
            F0.v = A0.v; F1.v = A1.v;
            const char* base = (const char*)sXT[cur] + sub * 16384;
#pragma unroll
            for (int ct = 0; ct < 4; ++ct) {
                int c = ch * 128 + ct * 32 + jl;
                int R = c >> 1;
                int off0 = (((c & 1) << 6) | (16 * g)) ^ SWZ8(R);
                int off1 = (((c & 1) << 6) | (32 + 16 * g)) ^ SWZ8(R);
                short8 bf0 = *(const short8*)(base + R * 128 + off0);
                short8 bf1 = *(const short8*)(base + R * 128 + off1);
                oAcc[ct] = __builtin_amdgcn_mfma_f32_32x32x16_bf16(F0.s, bf0, oAcc[ct], 0, 0, 0);
                oAcc[ct] = __builtin_amdgcn_mfma_f32_32x32x16_bf16(F1.s, bf1, oAcc[ct], 0, 0, 0);
            }
        }
        // drain only this iter's 8 stage ops (oldest); keep 4 P loads in flight
        asm volatile("s_waitcnt vmcnt(4)" ::: "memory");
        __builtin_amdgcn_sched_barrier(0);
        __builtin_amdgcn_s_barrier();
        __builtin_amdgcn_sched_barrier(0);
        cur ^= 1;
        a[0] = n[0]; a[1] = n[1]; a[2] = n[2]; a[3] = n[3];
    }

    den += __shfl_xor(den, 32);
    if (ch == 0 && lane < 32 && myrow < Mv)
        atomicAdd(&wsF[OFF_DEN + myrow], den);
#pragma unroll
    for (int ct = 0; ct < 4; ++ct) {
        int col = ch * 128 + ct * 32 + jl;
#pragma unroll
        for (int r = 0; r < 16; ++r) {
            int row = ibase + (r & 3) + 8 * (r >> 2) + 4 * g;
            if (row < Mv)
                atomicAdd(&wsF[OFF_OUT + (size_t)row * CDIM + col], oAcc[ct][r]);
        }
    }
}

// pass2 fallback: recompute QK (R9 structure)
__global__ __launch_bounds__(256, 2) void k5c_full(float* __restrict__ wsF, const int* __restrict__ wsI) {
    const int Mv = wsI[II_M];
    const int i0 = blockIdx.x * RPBF;
    if (i0 >= Mv) return;
    __shared__ __align__(16) ushort sK[2][32 * CDIM];
    __shared__ __align__(16) ushort sXT[2][CDIM * 32];
    const int tid = threadIdx.x;
    const int wave = tid >> 6, lane = tid & 63;
    const int jl = lane & 31, g = lane >> 5;
    const int pair = wave >> 1, ch = wave & 1;
    const char* XnBb = (const char*)(wsF + OFF_XNB);
    const char* XTBb = (const char*)(wsF + OFF_XTB);
    const unsigned* nmask = (const unsigned*)(wsI + II_NMASK);
    const int* anoIdx = wsI + II_ANOIDX;
    const int jc0 = blockIdx.y * JCHF;
    const int ibase = i0 + pair * 32;
    const int myrow = ibase + jl;

    short8 qf[16];
    float ec, thr;
    {
        int ii = min(myrow, Mv - 1);
        int arow = anoIdx[ii];
#pragma unroll
        for (int kc = 0; kc < 16; ++kc)
            qf[kc] = *(const short8*)(XnBb + (size_t)arow * 512 + kc * 32 + g * 16);
        ec = -__log2f(wsF[OFF_Z + ii]) - L2E;
        thr = wsF[OFF_THR + ii];
    }
    float den = 0.f;
    f32x16 oAcc[4];
#pragma unroll
    for (int ct = 0; ct < 4; ++ct)
#pragma unroll
        for (int r = 0; r < 16; ++r) oAcc[ct][r] = 0.f;

    auto stageK = [&](int buf, int j0) {
#pragma unroll
        for (int itr = 0; itr < 4; ++itr) {
            int d = ((itr * 256 + tid) << 4);
            int row = d >> 9;
            int srco = (d & ~511) | ((d & 511) ^ SWZ8(row));
            gld_lds16(XnBb + ((size_t)j0 << 9) + srco, (char*)sK[buf] + d);
        }
    };
    auto stageX = [&](int buf, int j0) {
#pragma unroll
        for (int itr = 0; itr < 4; ++itr) {
            int d = ((itr * 256 + tid) << 4);
            int R = d >> 7;
            int q = (d & 127) ^ SWZ8(R);
            int c = 2 * R + (q >> 6);
            gld_lds16(XTBb + (size_t)c * (P_TOT * 2) + ((size_t)j0 << 1) + (q & 63),
                      (char*)sXT[buf] + d);
        }
    };

    stageK(0, jc0);
    stageX(0, jc0);
    __syncthreads();
    int cur = 0;
    for (int js = 0; js < NJSF; ++js) {
        int j0 = jc0 + js * 32;
        if (js + 1 < NJSF) { stageK(cur ^ 1, j0 + 32); stageX(cur ^ 1, j0 + 32); }
        f32x16 acc;
#pragma unroll
        for (int r = 0; r < 16; ++r) acc[r] = 0.f;
#pragma unroll
        for (int kc = 0; kc < 16; ++kc) {
            int aoff = jl * 512 + ((kc * 32 + g * 16) ^ SWZ8(jl));
            short8 af = *(const short8*)((const char*)sK[cur] + aoff);
            acc = __builtin_amdgcn_mfma_f32_32x32x16_bf16(af, qf[kc], acc, 0, 0, 0);
        }
        unsigned um = nmask[j0 >> 5];
        float sw[16];
#pragma unroll
        for (int r = 0; r < 16; ++r) {
            int jr = (r & 3) + 8 * (r >> 2) + 4 * g;
            float w = __builtin_amdgcn_exp2f(fmaf(acc[r], L2E, ec));
            bool ok = (((um >> jr) & 1u) != 0u) && (w > thr);
            sw[r] = ok ? w : 0.f;
            den += sw[r];
        }
#pragma unroll
        for (int kk = 0; kk < 2; ++kk) {
            int s = 8 * kk;
            unsigned p0 = cvtpk(sw[s + 0], sw[s + 1]);
            unsigned p1 = cvtpk(sw[s + 2], sw[s + 3]);
            unsigned p2 = cvtpk(sw[s + 4], sw[s + 5]);
            unsigned p3 = cvtpk(sw[s + 6], sw[s + 7]);
            unsigned o0 = (unsigned)__shfl_xor((int)p0, 32);
            unsigned o1 = (unsigned)__shfl_xor((int)p1, 32);
            unsigned o2 = (unsigned)__shfl_xor((int)p2, 32);
            unsigned o3 = (unsigned)__shfl_xor((int)p3, 32);
            union { unsigned u[4]; short8 v; } fr;
            fr.u[0] = g ? o2 : p0;
            fr.u[1] = g ? o3 : p1;
            fr.u[2] = g ? p2 : o0;
            fr.u[3] = g ? p3 : o1;
#pragma unroll
            for (int ct = 0; ct < 4; ++ct) {
                int c = ch * 128 + ct * 32 + jl;
                int R = c >> 1;
                int off = (((c & 1) << 6) | (32 * kk + 16 * g)) ^ SWZ8(R);
                short8 bf = *(const short8*)((const char*)sXT[cur] + R * 128 + off);
                oAcc[ct] = __builtin_amdgcn_mfma_f32_32x32x16_bf16(fr.v, bf, oAcc[ct], 0, 0, 0);
            }
        }
        __syncthreads();
        cur ^= 1;
    }

    den += __shfl_xor(den, 32);
    if (ch == 0 && lane < 32 && myrow < Mv)
        atomicAdd(&wsF[OFF_DEN + myrow], den);
#pragma unroll
    for (int ct = 0; ct < 4; ++ct) {
        int col = ch * 128 + ct * 32 + jl;
#pragma unroll
        for (int r = 0; r < 16; ++r) {
            int row = ibase + (r & 3) + 8 * (r >> 2) + 4 * g;
            if (row < Mv)
                atomicAdd(&wsF[OFF_OUT + (size_t)row * CDIM + col], oAcc[ct][r]);
        }
    }
}

__global__ void k4d_final(float* __restrict__ out, const float* __restrict__ wsF,
                          const int* __restrict__ wsI) {
    int Mv = wsI[II_M];
    int i0 = blockIdx.x * TI;
    if (i0 >= Mv) return;
    int tid = threadIdx.x;
    int ii = tid >> 3, cg = tid & 7;
    int i = i0 + ii;
    if (i >= Mv) return;
    int p = wsI[II_ANOIDX + i];
    int b = p >> 10, n = p & 1023;
    float rden = 1.f / wsF[OFF_DEN + i];
    const float* go = wsF + OFF_OUT + (size_t)i * CDIM;
    float* op = out + (size_t)b * CDIM * NPIX + n;
#pragma unroll
    for (int cc = 0; cc < 32; ++cc) {
        int c = cc * 8 + cg;
        op[(size_t)c * NPIX] = go[c] * rden;
    }
}

extern "C" void kernel_launch(void* const* d_in, const int* in_sizes, int n_in,
                              void* d_out, int out_size, void* d_ws, size_t ws_size,
                              hipStream_t stream) {
    const float* f = (const float*)d_in[0];
    const float* center = (const float*)d_in[1];
    const float* Tc = (const float*)d_in[2];
    float* out = (float*)d_out;
    float* wsF = (float*)d_ws;
    int* wsI = (int*)(wsF + IOFF_BASE);
    const bool big = ws_size >= WS_NEED;
    ushort* Pbuf = (ushort*)((char*)d_ws + PB_OFF);

    hipMemsetAsync(wsF + OFF_Z, 0, (OFF_CT - OFF_Z) * sizeof(float), stream);
    hipMemsetAsync(wsI + II_M, 0, 2 * sizeof(int), stream);

    k0_prep<<<1, 256, 0, stream>>>(center, wsF);
    dim3 g1a(32, 8);
    k1a_dot<<<g1a, 256, 0, stream>>>(f, wsF + OFF_CT, wsF + OFF_PART);
    k1b_min<<<32, 256, 0, stream>>>(Tc, wsF + OFF_C2, wsF + OFF_PART, wsF, wsI);
    // OUT memset must come after k1b (PART aliases the OUT region)
    hipMemsetAsync(wsF + OFF_OUT, 0, (size_t)P_TOT * CDIM * sizeof(float), stream);
    dim3 g2(32, 8, 8), b2(32, 8);
    k2_convert<<<g2, b2, 0, stream>>>(f, out, wsF);
    k3_ld<<<1, 1, 0, stream>>>(out, wsF, wsI);
    dim3 g5a(P_TOT / RPBA, JSPA);
    k5aP<<<g5a, 256, 0, stream>>>(wsF, wsI, Pbuf, big ? 1 : 0);
    k4b_thr<<<P_TOT / 256, 256, 0, stream>>>(wsF, wsI);
    if (big) {
        // 1-D grid: lid = x*8 + y; y = lid & 7 keeps same-y blocks on one XCD
        k5cP<<<(P_TOT / RPBC) * JSPC, 256, 0, stream>>>(wsF, wsI, Pbuf);
    } else {
        dim3 g5c(P_TOT / RPBF, JSPF);
        k5c_full<<<g5c, 256, 0, stream>>>(wsF, wsI);
    }
    k4d_final<<<P_TOT / TI, 256, 0, stream>>>(out, wsF, wsI);
}